// Round 4
// baseline (517.855 us; speedup 1.0000x reference)
//
#include <hip/hip_runtime.h>
#include <hip/hip_bf16.h>
#include <math.h>

#define B_N   1024
#define M_N   200000
#define DIN   256
#define DIMN  128
#define DOUT  10
#define EPS_F 1e-7f
#define M_PAD 200064   // 1563 * 128
#define NBY   1563     // M_PAD / 128
#define NBX_C 1563     // candidate encode blocks
#define NBX_X 8        // x encode blocks
#define CTILES 8
#define NGY   196      // ceil(NBY / CTILES)

typedef __bf16 bf16_t;
typedef __bf16 bf16x8 __attribute__((ext_vector_type(8)));
typedef float  f32x4  __attribute__((ext_vector_type(4)));

// ---------- prep: W fp32->bf16 cvt + class histogram (merged) ----------

__global__ void prep_kernel(const float* __restrict__ W, bf16_t* __restrict__ Wb,
                            const int* __restrict__ cy, int* __restrict__ hist){
    __shared__ int h[DOUT];
    if (threadIdx.x < DOUT) h[threadIdx.x] = 0;
    __syncthreads();
    int gid = blockIdx.x*256 + threadIdx.x;      // grid 256 blocks -> 65536 threads
    if (gid < DIMN*DIN) Wb[gid] = (bf16_t)W[gid];
    for (int i = gid; i < M_N; i += 256*256)
        atomicAdd(&h[cy[i]], 1);
    __syncthreads();
    if (threadIdx.x < DOUT) atomicAdd(&hist[threadIdx.x*16], h[threadIdx.x]);  // padded lines
}

__global__ void prefix_kernel(const int* __restrict__ hist, int* __restrict__ cs){
    if (threadIdx.x == 0 && blockIdx.x == 0){
        int acc = 0;
        for (int c = 0; c < DOUT; ++c){ cs[c] = acc; acc += hist[c*16]; }
        cs[DOUT] = acc;   // == M_N
    }
}

// ---------- encoder (candidates + x merged): out[pos[m]] = bf16(src[m] @ Wb^T) ----------
// K=256 in two LDS-staged halves; half-1 global loads prefetched into registers
// BEFORE half-0 compute so they fly under the MFMAs.

__global__ __launch_bounds__(256) void encode_kernel(
    const float* __restrict__ cx, const float* __restrict__ xx,
    const bf16_t* __restrict__ Wb,
    bf16_t* __restrict__ hcb, bf16_t* __restrict__ hb,
    float* __restrict__ hcn, float* __restrict__ hn,
    const int* __restrict__ cy, int* __restrict__ counters,
    const int* __restrict__ cs)
{
    __shared__ bf16_t As[128][136];   // 34 KB
    __shared__ int   posL[128];
    __shared__ float nbuf[128][2];
    __shared__ int   cntL[DOUT], baseL[DOUT];
    const int tid = threadIdx.x;

    const bool isC = (blockIdx.x < NBX_C);
    const float* __restrict__ src = isC ? cx : xx;
    bf16_t* __restrict__ out   = isC ? hcb : hb;
    float*  __restrict__ onorm = isC ? hcn : hn;
    const int N  = isC ? M_N : B_N;
    const int r0 = (isC ? blockIdx.x : blockIdx.x - NBX_C)*128;

    int myc = -1, myrank = 0;
    if (isC){
        if (tid < DOUT) cntL[tid] = 0;
        __syncthreads();
        if (tid < 128 && r0 + tid < N){
            myc = cy[r0 + tid];
            myrank = atomicAdd(&cntL[myc], 1);        // LDS atomic: block-local rank
        }
        __syncthreads();
        if (tid < DOUT && cntL[tid] > 0)
            baseL[tid] = atomicAdd(&counters[tid*16], cntL[tid]);  // padded lines
        __syncthreads();
    }
    if (tid < 128)
        posL[tid] = (myc >= 0) ? (cs[myc] + baseL[myc] + myrank) : (r0 + tid);

    const int lane = tid & 63, wid = tid >> 6;
    const int wr = wid >> 1, wc = wid & 1;
    const int l15 = lane & 15, quad = lane >> 4;
    const int cbase = wc*64;

    float4 Rlo[8], Rhi[8];
    // load half 0
    #pragma unroll
    for (int i = 0; i < 8; ++i){
        int idx = i*256 + tid, row = idx >> 4, col = (idx & 15)*8;
        int rr = r0 + row; if (rr > N-1) rr = N-1;
        const float4* p4 = (const float4*)(src + (size_t)rr*DIN + col);
        Rlo[i] = p4[0]; Rhi[i] = p4[1];
    }
    // cvt + store half 0
    #pragma unroll
    for (int i = 0; i < 8; ++i){
        int idx = i*256 + tid, row = idx >> 4, col = (idx & 15)*8;
        float4 f0 = Rlo[i], f1 = Rhi[i];
        bf16x8 v;
        v[0]=(bf16_t)f0.x; v[1]=(bf16_t)f0.y; v[2]=(bf16_t)f0.z; v[3]=(bf16_t)f0.w;
        v[4]=(bf16_t)f1.x; v[5]=(bf16_t)f1.y; v[6]=(bf16_t)f1.z; v[7]=(bf16_t)f1.w;
        *(bf16x8*)&As[row][col] = v;
    }
    __syncthreads();
    // prefetch half 1 -> registers (in flight during half-0 compute)
    #pragma unroll
    for (int i = 0; i < 8; ++i){
        int idx = i*256 + tid, row = idx >> 4, col = (idx & 15)*8;
        int rr = r0 + row; if (rr > N-1) rr = N-1;
        const float4* p4 = (const float4*)(src + (size_t)rr*DIN + 128 + col);
        Rlo[i] = p4[0]; Rhi[i] = p4[1];
    }

    f32x4 acc[4][4] = {};
    #pragma unroll
    for (int ks = 0; ks < 4; ++ks){
        const int k = ks*32 + quad*8;
        bf16x8 a[4], b[4];
        #pragma unroll
        for (int rt = 0; rt < 4; ++rt)
            a[rt] = *(const bf16x8*)&As[wr*64 + rt*16 + l15][k];
        #pragma unroll
        for (int ct = 0; ct < 4; ++ct)
            b[ct] = *(const bf16x8*)(Wb + (size_t)(cbase + ct*16 + l15)*DIN + k);
        #pragma unroll
        for (int rt = 0; rt < 4; ++rt)
            #pragma unroll
            for (int ct = 0; ct < 4; ++ct)
                acc[rt][ct] = __builtin_amdgcn_mfma_f32_16x16x32_bf16(a[rt], b[ct], acc[rt][ct], 0, 0, 0);
    }
    __syncthreads();
    // cvt + store half 1
    #pragma unroll
    for (int i = 0; i < 8; ++i){
        int idx = i*256 + tid, row = idx >> 4, col = (idx & 15)*8;
        float4 f0 = Rlo[i], f1 = Rhi[i];
        bf16x8 v;
        v[0]=(bf16_t)f0.x; v[1]=(bf16_t)f0.y; v[2]=(bf16_t)f0.z; v[3]=(bf16_t)f0.w;
        v[4]=(bf16_t)f1.x; v[5]=(bf16_t)f1.y; v[6]=(bf16_t)f1.z; v[7]=(bf16_t)f1.w;
        *(bf16x8*)&As[row][col] = v;
    }
    __syncthreads();
    #pragma unroll
    for (int ks = 0; ks < 4; ++ks){
        const int k = ks*32 + quad*8;
        bf16x8 a[4], b[4];
        #pragma unroll
        for (int rt = 0; rt < 4; ++rt)
            a[rt] = *(const bf16x8*)&As[wr*64 + rt*16 + l15][k];
        #pragma unroll
        for (int ct = 0; ct < 4; ++ct)
            b[ct] = *(const bf16x8*)(Wb + (size_t)(cbase + ct*16 + l15)*DIN + 128 + k);
        #pragma unroll
        for (int rt = 0; rt < 4; ++rt)
            #pragma unroll
            for (int ct = 0; ct < 4; ++ct)
                acc[rt][ct] = __builtin_amdgcn_mfma_f32_16x16x32_bf16(a[rt], b[ct], acc[rt][ct], 0, 0, 0);
    }

    // ||row||^2: per-lane partial over 4 cols, butterfly over 16-lane col group
    float np[4][4];
    #pragma unroll
    for (int rt = 0; rt < 4; ++rt)
        #pragma unroll
        for (int r = 0; r < 4; ++r){
            float s = 0.f;
            #pragma unroll
            for (int ct = 0; ct < 4; ++ct){ float v = acc[rt][ct][r]; s += v*v; }
            np[rt][r] = s;
        }
    #pragma unroll
    for (int m = 1; m < 16; m <<= 1)
        #pragma unroll
        for (int rt = 0; rt < 4; ++rt)
            #pragma unroll
            for (int r = 0; r < 4; ++r)
                np[rt][r] += __shfl_xor(np[rt][r], m, 64);
    if (l15 == 0){
        #pragma unroll
        for (int rt = 0; rt < 4; ++rt)
            #pragma unroll
            for (int r = 0; r < 4; ++r)
                nbuf[wr*64 + rt*16 + quad*4 + r][wc] = np[rt][r];
    }

    // scatter-store bf16 rows (C/D layout: col = l15, row = quad*4 + r)
    #pragma unroll
    for (int rt = 0; rt < 4; ++rt){
        #pragma unroll
        for (int r = 0; r < 4; ++r){
            int rl = wr*64 + rt*16 + quad*4 + r;
            if (r0 + rl < N){
                size_t rowp = (size_t)posL[rl]*DIMN;
                #pragma unroll
                for (int ct = 0; ct < 4; ++ct)
                    out[rowp + cbase + ct*16 + l15] = (bf16_t)acc[rt][ct][r];
            }
        }
    }
    __syncthreads();
    if (tid < 128){
        int rs = r0 + tid;
        if (rs < N) onorm[posL[tid]] = nbuf[tid][0] + nbuf[tid][1];
    }
}

// ---------- fused dist -> exp -> class-segmented row sums ----------
// AITER-style K-loop: double-buffered LDS filled by async global_load_lds(16B),
// issued right after the single per-tile barrier so the loads fly under the
// whole compute phase. Unpadded LDS + XOR-swizzled global fetch keeps the
// ds_read_b128 bank distribution optimal (8 groups x 8 lanes).

__device__ __forceinline__ void bfly16(float (&s)[4][4]){
    #pragma unroll
    for (int m = 1; m < 16; m <<= 1)
        #pragma unroll
        for (int rt = 0; rt < 4; ++rt)
            #pragma unroll
            for (int r = 0; r < 4; ++r)
                s[rt][r] += __shfl_xor(s[rt][r], m, 64);
}

__device__ __forceinline__ void flushC(float (&s)[4][4], int c, int rbase,
                                       int quad, int l15, float* __restrict__ accG){
    bfly16(s);
    if (l15 == 0){
        #pragma unroll
        for (int rt = 0; rt < 4; ++rt)
            #pragma unroll
            for (int r = 0; r < 4; ++r)
                atomicAdd(&accG[(size_t)(rbase + rt*16 + quad*4 + r)*16 + c], s[rt][r]);
    }
}

__global__ __launch_bounds__(256) void fused_kernel(
    const bf16_t* __restrict__ hb, const bf16_t* __restrict__ hcb,
    const float* __restrict__ hn, const float* __restrict__ hcn,
    const int* __restrict__ csg, float* __restrict__ accG)
{
    __shared__ bf16_t Bs[2][128*DIMN];   // 2 x 32 KB, unpadded, chunk-swizzled
    const int tid = threadIdx.x;
    const int lane = tid & 63, wid = tid >> 6;
    const int wr = wid >> 1, wc = wid & 1;
    const int l15 = lane & 15, quad = lane >> 4;
    const int rbase = blockIdx.x*128 + wr*64;
    const int lrow = lane >> 4, lpos = lane & 15;

    const int by0 = blockIdx.y*CTILES;
    const int nt  = min(CTILES, NBY - by0);

    // A fragments: fixed per block, held in registers
    bf16x8 a[4][4];
    #pragma unroll
    for (int ks = 0; ks < 4; ++ks)
        #pragma unroll
        for (int rt = 0; rt < 4; ++rt)
            a[ks][rt] = *(const bf16x8*)(hb + (size_t)(rbase + rt*16 + l15)*DIMN + ks*32 + quad*8);

    float hnv[4][4];
    #pragma unroll
    for (int rt = 0; rt < 4; ++rt)
        #pragma unroll
        for (int r = 0; r < 4; ++r)
            hnv[rt][r] = hn[rbase + rt*16 + quad*4 + r];

    int cseg[DOUT+1];
    #pragma unroll
    for (int i = 0; i <= DOUT; ++i) cseg[i] = csg[i];

    // async stage one 128x128 bf16 tile: 8 x 1KB gll per wave.
    // lane fetches global chunk (lpos ^ row15) so LDS[row][pos] = chunk (pos ^ row15).
    auto stage = [&](int buf, int by){
        const size_t gr0 = (size_t)by*128;
        #pragma unroll
        for (int j = 0; j < 8; ++j){
            int g  = wid*8 + j;              // 1KB group, wave-uniform
            int rl = g*4 + lrow;             // local row 0..127
            int ck = lpos ^ (rl & 15);       // swizzled global chunk
            const bf16_t* gp = hcb + (gr0 + rl)*DIMN + ck*8;
            bf16_t* lp = &Bs[buf][g*512];    // uniform base; lane i -> +i*16B
            __builtin_amdgcn_global_load_lds(
                (const __attribute__((address_space(1))) void*)gp,
                (__attribute__((address_space(3))) void*)lp, 16, 0, 0);
        }
    };

    stage(0, by0);
    float s[4][4] = {};
    int curC = -1;

    for (int t = 0; t < nt; ++t){
        __syncthreads();                      // drains tile t's gll; prev readers done
        if (t+1 < nt) stage((t+1)&1, by0 + t + 1);   // flies under this compute
        const int cbase0 = (by0 + t)*128;
        const bf16_t* bs = Bs[t&1];

        f32x4 acc[4][4] = {};
        #pragma unroll
        for (int ks = 0; ks < 4; ++ks){
            bf16x8 b[4];
            #pragma unroll
            for (int ct = 0; ct < 4; ++ct){
                int cand = wc*64 + ct*16 + l15;
                int p    = (ks*4 + quad) ^ l15;      // de-swizzle
                b[ct] = *(const bf16x8*)(bs + cand*DIMN + p*8);
            }
            #pragma unroll
            for (int rt = 0; rt < 4; ++rt)
                #pragma unroll
                for (int ct = 0; ct < 4; ++ct)
                    acc[rt][ct] = __builtin_amdgcn_mfma_f32_16x16x32_bf16(a[ks][rt], b[ct], acc[rt][ct], 0, 0, 0);
        }

        // epilogue: prob = exp(-sqrt(max(|h|^2 + |hc|^2 - 2 dot, 0)))
        float hcnv[4];
        #pragma unroll
        for (int ct = 0; ct < 4; ++ct){
            int cc = cbase0 + wc*64 + ct*16 + l15;
            hcnv[ct] = (cc < M_N) ? hcn[cc] : 1e30f;   // pad/garbage cols -> exp == 0
        }
        #pragma unroll
        for (int rt = 0; rt < 4; ++rt)
            #pragma unroll
            for (int ct = 0; ct < 4; ++ct)
                #pragma unroll
                for (int r = 0; r < 4; ++r){
                    float sq = fmaxf(hnv[rt][r] + hcnv[ct] - 2.0f*acc[rt][ct][r], 0.0f);
                    acc[rt][ct][r] = __expf(-__builtin_amdgcn_sqrtf(sq));
                }

        // class span (block-uniform); candidates are class-sorted
        const int lastc = min(cbase0 + 127, M_N - 1);
        int cLo = 0, cHi = 0;
        #pragma unroll
        for (int c = 1; c < DOUT; ++c){
            if (cbase0 >= cseg[c]) cLo = c;
            if (lastc  >= cseg[c]) cHi = c;
        }

        if (cLo == curC && cHi == curC){
            #pragma unroll
            for (int rt = 0; rt < 4; ++rt)
                #pragma unroll
                for (int r = 0; r < 4; ++r){
                    float v = 0.f;
                    #pragma unroll
                    for (int ct = 0; ct < 4; ++ct) v += acc[rt][ct][r];
                    s[rt][r] += v;
                }
        } else {
            if (curC >= 0) flushC(s, curC, rbase, quad, l15, accG);
            #pragma unroll
            for (int rt = 0; rt < 4; ++rt)
                #pragma unroll
                for (int r = 0; r < 4; ++r) s[rt][r] = 0.f;
            for (int c = cLo; c <= cHi; ++c){
                const int s0 = cseg[c], s1 = cseg[c+1];
                float m[4][4];
                #pragma unroll
                for (int rt = 0; rt < 4; ++rt)
                    #pragma unroll
                    for (int r = 0; r < 4; ++r){
                        float v = 0.f;
                        #pragma unroll
                        for (int ct = 0; ct < 4; ++ct){
                            int cc = cbase0 + wc*64 + ct*16 + l15;
                            v += (cc >= s0 && cc < s1) ? acc[rt][ct][r] : 0.f;
                        }
                        m[rt][r] = v;
                    }
                if (c == cHi){
                    #pragma unroll
                    for (int rt = 0; rt < 4; ++rt)
                        #pragma unroll
                        for (int r = 0; r < 4; ++r) s[rt][r] = m[rt][r];
                    curC = cHi;
                } else {
                    flushC(m, c, rbase, quad, l15, accG);
                }
            }
        }
    }
    if (curC >= 0) flushC(s, curC, rbase, quad, l15, accG);
}

__global__ void finalize_kernel(const float* __restrict__ accG, float* __restrict__ out){
    int b = blockIdx.x*blockDim.x + threadIdx.x;
    if (b < B_N){
        float v[DOUT]; float den = 0.f;
        #pragma unroll
        for (int c = 0; c < DOUT; ++c){ v[c] = accG[b*16 + c]; den += v[c]; }
        float inv = (den > 0.f) ? 1.0f/den : 0.f;
        #pragma unroll
        for (int c = 0; c < DOUT; ++c) out[b*DOUT + c] = logf(v[c]*inv + EPS_F);
    }
}

// ---------- launch ----------

extern "C" void kernel_launch(void* const* d_in, const int* in_sizes, int n_in,
                              void* d_out, int out_size, void* d_ws, size_t ws_size,
                              hipStream_t stream)
{
    const float* x  = (const float*)d_in[0];
    // d_in[1] = y (unused on eval path)
    const float* cx = (const float*)d_in[2];
    const int*   cy = (const int*)d_in[3];
    const float* W  = (const float*)d_in[4];
    // d_in[5] = b_enc: cancels exactly in ||h - hc||, skipped
    // d_in[6] = is_train (eval path)
    float* out = (float*)d_out;

    char* w = (char*)d_ws;
    size_t off = 0;
    bf16_t* hcb = (bf16_t*)(w + off); off += (size_t)M_PAD*DIMN*2;  // 51,216,384
    bf16_t* hb  = (bf16_t*)(w + off); off += (size_t)B_N*DIMN*2;    //    262,144
    float*  hcn = (float*) (w + off); off += (size_t)M_PAD*4;       //    800,256
    float*  hn  = (float*) (w + off); off += (size_t)B_N*4;         //      4,096
    bf16_t* Wb  = (bf16_t*)(w + off); off += (size_t)DIMN*DIN*2;    //     65,536
    size_t zoff = off;
    float* accG = (float*)(w + off); off += (size_t)B_N*16*4;       //     65,536
    int* hist     = (int*)(w + off); off += 16*DOUT*4;              // line-padded
    int* counters = (int*)(w + off); off += 16*DOUT*4;              // line-padded
    int* csg      = (int*)(w + off); off += 64;
    size_t zsize = off - zoff;

    hipMemsetAsync(w + zoff, 0, zsize, stream);
    prep_kernel<<<dim3(256), dim3(256), 0, stream>>>(W, Wb, cy, hist);
    prefix_kernel<<<dim3(1), dim3(1), 0, stream>>>(hist, csg);
    encode_kernel<<<dim3(NBX_C + NBX_X), dim3(256), 0, stream>>>(cx, x, Wb, hcb, hb, hcn, hn, cy, counters, csg);
    fused_kernel<<<dim3(B_N/128, NGY), dim3(256), 0, stream>>>(hb, hcb, hn, hcn, csg, accG);
    finalize_kernel<<<dim3((B_N + 255)/256), dim3(256), 0, stream>>>(accG, out);
}